// Round 22
// baseline (98.691 us; speedup 1.0000x reference)
//
#include <hip/hip_runtime.h>

typedef unsigned int u32;
typedef unsigned short u16;
typedef __fp16 h2 __attribute__((ext_vector_type(2)));
typedef __fp16 f16x8 __attribute__((ext_vector_type(8)));
typedef float f32x4 __attribute__((ext_vector_type(4)));

#define DEVFN static __device__ __forceinline__

DEVFN u32 pkh(float a, float b) {
  return __builtin_bit_cast(u32, __builtin_amdgcn_cvt_pkrtz(a, b));
}
DEVFN u16 f2h(float f) { __fp16 h = (__fp16)f; return __builtin_bit_cast(u16, h); }

#if __has_builtin(__builtin_amdgcn_fdot2)
DEVFN float dot2u(u32 a, u32 b, float c) {
  return __builtin_amdgcn_fdot2(__builtin_bit_cast(h2, a),
                                __builtin_bit_cast(h2, b), c, false);
}
#else
DEVFN float dot2u(u32 a, u32 b, float c) {
  h2 x = __builtin_bit_cast(h2, a), y = __builtin_bit_cast(h2, b);
  return c + (float)x[0] * (float)y[0] + (float)x[1] * (float)y[1];
}
#endif

DEVFN uint4 pk8(f32x4 lo, f32x4 hi) {
  uint4 o;
  o.x = pkh(lo.x, lo.y); o.y = pkh(lo.z, lo.w);
  o.z = pkh(hi.x, hi.y); o.w = pkh(hi.z, hi.w);
  return o;
}

DEVFN void gld16(const u16* g, u16* l) {
  __builtin_amdgcn_global_load_lds(
      (const __attribute__((address_space(1))) u32*)g,
      (__attribute__((address_space(3))) u32*)l, 16, 0, 0);
}

DEVFN void waitl0() { asm volatile("s_waitcnt lgkmcnt(0)" ::: "memory"); }
DEVFN void rbar() {
  __builtin_amdgcn_sched_barrier(0);
  __builtin_amdgcn_s_barrier();
  __builtin_amdgcn_sched_barrier(0);
}

// GEMM1: C = A @ B^T, f32 reg-staged dbuf raw-barrier pipeline (r21 verified).
// BM=128 x BN=512, 512 threads (8 waves 2x4), 256 blocks (1/CU).
// A depth-3 prefetch (two named reg sets), B depth-2.
// Epilogue: per-64-col-group L2 norm, scatter to PLANAR qf
// [sel][b][t][h][1024px][64] f16, fr = ((sel*2+b)*8+t)*8+h.
__global__ __launch_bounds__(512) void gemm1(
    const float* __restrict__ Af, const float* __restrict__ Bf,
    u16* __restrict__ Out, int Nn, int K) {
  __shared__ u16 As[2][4096];    // [128][32]
  __shared__ u16 Bs[2][16384];   // [512][32]
  const int tid = threadIdx.x;
  const int lane = tid & 63;
  const int w = tid >> 6;
  const int wm = w >> 2, wn = w & 3;
  const int nwg = (int)gridDim.x;     // 256
  const int wg = ((int)blockIdx.x & 7) * (nwg >> 3) + ((int)blockIdx.x >> 3);
  const int tm = wg >> 1, tn = wg & 1;

  const int ra = tid >> 2;
  const int s8 = (tid & 3) << 3;
  const size_t offA = (size_t)(tm * 128 + ra) * K + s8;
  const size_t offB = (size_t)(tn * 512 + ra) * K + s8;
  const int wofs = ra * 32 + s8;

  const int rofsA = ((wm * 64 + (lane & 15)) << 5) + ((lane >> 4) << 3);
  const int rofsB = ((wn * 128 + (lane & 15)) << 5) + ((lane >> 4) << 3);

  f32x4 acc[4][8] = {};
  f32x4 ae0, ae1, ao0, ao1;                       // A sets E / O
  f32x4 b0, b1, b2, b3, b4, b5, b6, b7;           // B set

#define LOADA_E(t)                                                        \
  {                                                                       \
    const size_t oa = offA + (size_t)(t) * 32;                            \
    ae0 = *(const f32x4*)(Af + oa);                                       \
    ae1 = *(const f32x4*)(Af + oa + 4);                                   \
  }
#define LOADA_O(t)                                                        \
  {                                                                       \
    const size_t oa = offA + (size_t)(t) * 32;                            \
    ao0 = *(const f32x4*)(Af + oa);                                       \
    ao1 = *(const f32x4*)(Af + oa + 4);                                   \
  }
#define LOADB(t)                                                          \
  {                                                                       \
    const size_t ob = offB + (size_t)(t) * 32;                            \
    b0 = *(const f32x4*)(Bf + ob);                                        \
    b1 = *(const f32x4*)(Bf + ob + 4);                                    \
    b2 = *(const f32x4*)(Bf + ob + (size_t)128 * K);                      \
    b3 = *(const f32x4*)(Bf + ob + (size_t)128 * K + 4);                  \
    b4 = *(const f32x4*)(Bf + ob + (size_t)256 * K);                      \
    b5 = *(const f32x4*)(Bf + ob + (size_t)256 * K + 4);                  \
    b6 = *(const f32x4*)(Bf + ob + (size_t)384 * K);                      \
    b7 = *(const f32x4*)(Bf + ob + (size_t)384 * K + 4);                  \
  }
#define WRITE_E(bufi)                                                     \
  {                                                                       \
    *(uint4*)(&As[bufi][wofs]) = pk8(ae0, ae1);                           \
    *(uint4*)(&Bs[bufi][wofs]) = pk8(b0, b1);                             \
    *(uint4*)(&Bs[bufi][wofs + 4096]) = pk8(b2, b3);                      \
    *(uint4*)(&Bs[bufi][wofs + 8192]) = pk8(b4, b5);                      \
    *(uint4*)(&Bs[bufi][wofs + 12288]) = pk8(b6, b7);                     \
  }
#define WRITE_O(bufi)                                                     \
  {                                                                       \
    *(uint4*)(&As[bufi][wofs]) = pk8(ao0, ao1);                           \
    *(uint4*)(&Bs[bufi][wofs]) = pk8(b0, b1);                             \
    *(uint4*)(&Bs[bufi][wofs + 4096]) = pk8(b2, b3);                      \
    *(uint4*)(&Bs[bufi][wofs + 8192]) = pk8(b4, b5);                      \
    *(uint4*)(&Bs[bufi][wofs + 12288]) = pk8(b6, b7);                     \
  }
#define FRAGS(bufi)                                                       \
  f16x8 af[4], bf[8];                                                     \
  _Pragma("unroll") for (int i = 0; i < 4; ++i)                           \
      af[i] = *(const f16x8*)(&As[bufi][rofsA + i * 512]);                \
  _Pragma("unroll") for (int i = 0; i < 8; ++i)                           \
      bf[i] = *(const f16x8*)(&Bs[bufi][rofsB + i * 512]);
#define MFMAS                                                             \
  __builtin_amdgcn_s_setprio(1);                                          \
  _Pragma("unroll") for (int mi = 0; mi < 4; ++mi)                        \
      _Pragma("unroll") for (int ni = 0; ni < 8; ++ni)                    \
          acc[mi][ni] = __builtin_amdgcn_mfma_f32_16x16x32_f16(           \
              af[mi], bf[ni], acc[mi][ni], 0, 0, 0);                      \
  __builtin_amdgcn_s_setprio(0);

  const int KT = K >> 5;   // 16 (even)
  LOADA_E(0)
  LOADB(0)
  WRITE_E(0)
  LOADA_O(1)
  LOADA_E(2)
  LOADB(1)
  waitl0();
  rbar();

  for (int kt = 0; kt < KT; kt += 2) {
    {  // even body
      FRAGS(0)
      if (kt + 1 < KT) {
        WRITE_O(1)
        if (kt + 2 < KT) LOADB(kt + 2)
        if (kt + 3 < KT) LOADA_O(kt + 3)
      }
      MFMAS
      waitl0();
      rbar();
    }
    {  // odd body
      FRAGS(1)
      if (kt + 2 < KT) {
        WRITE_E(0)
        if (kt + 3 < KT) LOADB(kt + 3)
        if (kt + 4 < KT) LOADA_E(kt + 4)
      }
      MFMAS
      waitl0();
      rbar();
    }
  }
#undef LOADA_E
#undef LOADA_O
#undef LOADB
#undef WRITE_E
#undef WRITE_O
#undef FRAGS
#undef MFMAS

  const int rowBase = tm * 128 + wm * 64 + ((lane >> 4) << 2);
  const int colLo = tn * 512 + wn * 128;
  const int colHi = colLo + 64;
  const int selLo = colLo >> 9, hhLo = (colLo >> 6) & 7;
  const int selHi = colHi >> 9, hhHi = (colHi >> 6) & 7;
  const int ddb = lane & 15;
#pragma unroll
  for (int mi = 0; mi < 4; ++mi)
#pragma unroll
    for (int r = 0; r < 4; ++r) {
      float sl = acc[mi][0][r] * acc[mi][0][r] + acc[mi][1][r] * acc[mi][1][r] +
                 acc[mi][2][r] * acc[mi][2][r] + acc[mi][3][r] * acc[mi][3][r];
      float sh = acc[mi][4][r] * acc[mi][4][r] + acc[mi][5][r] * acc[mi][5][r] +
                 acc[mi][6][r] * acc[mi][6][r] + acc[mi][7][r] * acc[mi][7][r];
      sl += __shfl_xor(sl, 1); sh += __shfl_xor(sh, 1);
      sl += __shfl_xor(sl, 2); sh += __shfl_xor(sh, 2);
      sl += __shfl_xor(sl, 4); sh += __shfl_xor(sh, 4);
      sl += __shfl_xor(sl, 8); sh += __shfl_xor(sh, 8);
      float invl = 1.0f / fmaxf(sqrtf(sl), 1e-12f);
      float invh = 1.0f / fmaxf(sqrtf(sh), 1e-12f);
      const int m = rowBase + mi * 16 + r;
      const int bb = m >> 13, tt = (m >> 10) & 7, pix = m & 1023;
      const size_t pxo = (size_t)pix * 64 + ddb;
      const int frL = ((selLo * 2 + bb) * 8 + tt) * 8 + hhLo;
      const int frH = ((selHi * 2 + bb) * 8 + tt) * 8 + hhHi;
      size_t baseL = (((size_t)frL) << 16) + pxo;
      size_t baseH = (((size_t)frH) << 16) + pxo;
#pragma unroll
      for (int ni = 0; ni < 4; ++ni) {
        Out[baseL + ni * 16] = f2h(acc[mi][ni][r] * invl);
        Out[baseH + ni * 16] = f2h(acc[mi][ni + 4][r] * invh);
      }
    }
}

// GEMM2b: out = A @ B^T + bias.  A [M][448] f16 (corr), B [512][448] f16 (W2).
// BM=64 x BN=128 -> 1024 blocks, BK=64 as two [.][32] subtiles/round.
__global__ __launch_bounds__(256) void gemm2b(
    const u16* __restrict__ A, const u16* __restrict__ B,
    const float* __restrict__ bias, float* __restrict__ Out,
    int Nn, int K) {
  __shared__ u16 As[2][2048];
  __shared__ u16 Bs[2][4096];
  const int tid = threadIdx.x;
  const int lane = tid & 63;
  const int w = tid >> 6;
  const int nwg = (int)gridDim.x;
  const int wg = ((int)blockIdx.x & 7) * (nwg >> 3) + ((int)blockIdx.x >> 3);
  const int tm = wg >> 2, tn = wg & 3;

  const u16* gA = A + (size_t)(tm * 64 + w * 16 + (lane >> 2)) * K +
                  ((lane & 3) << 3);
  const u16* gB = B + (size_t)(tn * 128 + w * 32 + (lane >> 2)) * K +
                  ((lane & 3) << 3);

  const int rofsA = ((lane & 15) << 5) + ((lane >> 4) << 3);
  const int rofsB = w * 1024 + ((lane & 15) << 5) + ((lane >> 4) << 3);

  f32x4 acc[4][2] = {};

#define STG(bufi, t)                                                      \
  {                                                                       \
    gld16(gA + (size_t)(t) * 32, &As[bufi][w * 512]);                     \
    gld16(gB + (size_t)(t) * 32, &Bs[bufi][w * 1024]);                    \
    gld16(gB + (size_t)(t) * 32 + (size_t)16 * K, &Bs[bufi][w * 1024 + 512]); \
  }

  const int KT = K >> 6;   // 448/64 = 7
  for (int kt = 0; kt < KT; ++kt) {
    __syncthreads();
    STG(0, 2 * kt)
    STG(1, 2 * kt + 1)
    __syncthreads();
#pragma unroll
    for (int sub = 0; sub < 2; ++sub) {
      f16x8 af[4], bf[2];
#pragma unroll
      for (int i = 0; i < 4; ++i)
        af[i] = *(const f16x8*)(&As[sub][rofsA + i * 512]);
#pragma unroll
      for (int i = 0; i < 2; ++i)
        bf[i] = *(const f16x8*)(&Bs[sub][rofsB + i * 512]);
#pragma unroll
      for (int mi = 0; mi < 4; ++mi)
#pragma unroll
        for (int ni = 0; ni < 2; ++ni)
          acc[mi][ni] = __builtin_amdgcn_mfma_f32_16x16x32_f16(
              af[mi], bf[ni], acc[mi][ni], 0, 0, 0);
    }
  }
#undef STG

  const int rowBase = tm * 64 + ((lane >> 4) << 2);
  const int colBase = tn * 128 + w * 32 + (lane & 15);
  float bv[2];
#pragma unroll
  for (int ni = 0; ni < 2; ++ni) bv[ni] = bias[colBase + ni * 16];
#pragma unroll
  for (int mi = 0; mi < 4; ++mi)
#pragma unroll
    for (int r = 0; r < 4; ++r) {
      size_t ro = (size_t)(rowBase + mi * 16 + r) * Nn;
#pragma unroll
      for (int ni = 0; ni < 2; ++ni)
        Out[ro + colBase + ni * 16] = acc[mi][ni][r] + bv[ni];
    }
}

// Merged, 256 threads: blocks 0..511 = dots (corr[448]); 512..1023 = W2/cvec.
// dots NEW: dual-pipe k reads — dv 0..3 via staged LDS (as before), dv 4..6
// directly from global qf (L2-resident k-plane). Splits the former 826MB
// LDS-read bottleneck across LDS (~52 TB/s) and L2 (~34.5 TB/s) in parallel.
__global__ __launch_bounds__(256) void dots_w2(
    const u16* __restrict__ qf, u16* __restrict__ corr,
    const float* __restrict__ wp, const float* __restrict__ wc,
    const float* __restrict__ bc, const float* __restrict__ bp,
    u16* __restrict__ W2, float* __restrict__ cvec) {
  __shared__ __align__(16) u16 smem[448 * 64];  // 56KB
  const int tid = threadIdx.x;

  if ((int)blockIdx.x >= 512) {
    const int o = (int)blockIdx.x - 512;
    float* wcl = (float*)smem;
    float* wpl = wcl + 3136;
    for (int i = tid; i < 3136; i += 256) wcl[i] = wc[i];
    wpl[tid] = wp[o * 512 + tid];
    wpl[tid + 256] = wp[o * 512 + tid + 256];
    __syncthreads();
#pragma unroll
    for (int pass = 0; pass < 2; ++pass) {
      const int idx = pass * 256 + tid;
      if (idx < 448) {
        const int hh = idx / 56, r = idx % 56, du = r >> 3, dv = r & 7;
        float sv = 0.f;
        if (dv < 7) {
#pragma unroll
          for (int c = 0; c < 64; ++c)
            sv += wpl[hh * 64 + c] * wcl[c * 49 + du * 7 + dv];
        }
        W2[o * 448 + idx] = f2h(sv);
      }
    }
    if (tid < 64) {
      float p = 0.f;
#pragma unroll
      for (int g = 0; g < 8; ++g) p += wpl[g * 64 + tid];
      p *= bc[tid];
      p += __shfl_xor(p, 1); p += __shfl_xor(p, 2); p += __shfl_xor(p, 4);
      p += __shfl_xor(p, 8); p += __shfl_xor(p, 16); p += __shfl_xor(p, 32);
      if (tid == 0) cvec[o] = p + bp[o];
    }
    return;
  }

  u16* kst = smem;
  const int bid = ((int)blockIdx.x & 7) * 64 + ((int)blockIdx.x >> 3);  // XCD
  const int fr = bid >> 2, grp = bid & 3;
  const int h = fr & 7, t = (fr >> 3) & 7, b = fr >> 6;
  const int t1 = (t < 7) ? t + 1 : 7;
  const int y0 = grp * 8;

  const u16* kbase = qf + (((size_t)(((2 + b) * 8 + t1) * 8 + h)) << 16);
  {
    const int ppx = tid >> 3;
    const int slot = tid & 7;
#pragma unroll
    for (int pass = 0; pass < 14; ++pass) {
      int gy = y0 - 3 + pass;
      uint4 v = make_uint4(0, 0, 0, 0);
      if ((unsigned)gy < 32u)
        v = *(const uint4*)(kbase + (size_t)(gy * 32 + ppx) * 64 + slot * 8);
      int pl = pass * 32 + ppx;
      *(uint4*)((char*)kst + pl * 128 + ((slot * 16) ^ ((pl & 7) << 4))) = v;
    }
  }

  const int px = grp * 256 + tid;
  const int x = tid & 31, yloc = tid >> 5;
  const int yabs = px >> 5;
  const u16* qp = qf + (((size_t)fr) << 16) + (size_t)px * 64;
  u32 qw[32];
#pragma unroll
  for (int j = 0; j < 8; ++j) {
    uint4 v = *(const uint4*)(qp + j * 8);
    qw[j * 4 + 0] = v.x; qw[j * 4 + 1] = v.y;
    qw[j * 4 + 2] = v.z; qw[j * 4 + 3] = v.w;
  }
  __syncthreads();

  u16* mp = corr + (size_t)((b * 8 + t) * 1024 + px) * 448 + h * 56;
  for (int du = 0; du < 7; ++du) {
    const int rlbase = (yloc + du) * 32;
    const int gy = yabs + du - 3;                  // absolute k row
    const unsigned rowok = ((unsigned)gy < 32u);
    const int gyc = gy < 0 ? 0 : (gy > 31 ? 31 : gy);
    const u16* krow = kbase + (size_t)(gyc * 32) * 64;
    float f[7];
    // dv 0..3: staged LDS path (OOB rows are zero-filled in LDS)
#pragma unroll
    for (int dv = 0; dv < 4; ++dv) {
      int xx = x + dv - 3;
      int xc = xx < 0 ? 0 : xx;                    // dv<4 -> xx <= x <= 31
      int pl = rlbase + xc;
      const char* kr = (const char*)kst + pl * 128;
      const int swz = (pl & 7) << 4;
      float s0 = 0.f, s1 = 0.f, s2 = 0.f, s3 = 0.f;
#pragma unroll
      for (int j = 0; j < 8; ++j) {
        uint4 v = *(const uint4*)(kr + ((j * 16) ^ swz));
        s0 = dot2u(qw[j * 4 + 0], v.x, s0);
        s1 = dot2u(qw[j * 4 + 1], v.y, s1);
        s2 = dot2u(qw[j * 4 + 2], v.z, s2);
        s3 = dot2u(qw[j * 4 + 3], v.w, s3);
      }
      float s = (s0 + s1) + (s2 + s3);
      f[dv] = ((unsigned)xx < 32u) ? s : 0.f;
    }
    // dv 4..6: direct global reads (k-plane L2-resident); xx >= 1 here
#pragma unroll
    for (int dv = 4; dv < 7; ++dv) {
      int xx = x + dv - 3;
      int xc = xx > 31 ? 31 : xx;
      const u16* kg = krow + (size_t)xc * 64;
      float s0 = 0.f, s1 = 0.f, s2 = 0.f, s3 = 0.f;
#pragma unroll
      for (int j = 0; j < 8; ++j) {
        uint4 v = *(const uint4*)(kg + j * 8);
        s0 = dot2u(qw[j * 4 + 0], v.x, s0);
        s1 = dot2u(qw[j * 4 + 1], v.y, s1);
        s2 = dot2u(qw[j * 4 + 2], v.z, s2);
        s3 = dot2u(qw[j * 4 + 3], v.w, s3);
      }
      float s = (s0 + s1) + (s2 + s3);
      f[dv] = (rowok && xx < 32) ? s : 0.f;
    }
    uint4 o;
    o.x = pkh(f[0], f[1]); o.y = pkh(f[2], f[3]);
    o.z = pkh(f[4], f[5]); o.w = pkh(f[6], 0.f);
    *(uint4*)(mp + du * 8) = o;
  }
}

extern "C" void kernel_launch(void* const* d_in, const int* in_sizes, int n_in,
                              void* d_out, int out_size, void* d_ws, size_t ws_size,
                              hipStream_t stream) {
  const float* x      = (const float*)d_in[0];  // [2,8192,512] f32
  const float* w_qk   = (const float*)d_in[1];  // [1024,512]   f32
  const float* w_corr = (const float*)d_in[2];  // [64,49]      f32
  const float* b_corr = (const float*)d_in[3];  // [64]         f32
  const float* w_proj = (const float*)d_in[4];  // [512,512]    f32
  const float* b_proj = (const float*)d_in[5];  // [512]        f32
  float* out = (float*)d_out;                   // [2,8192,512] f32

  u16* corr = (u16*)d_ws;
  u16* qf   = corr + (size_t)16384 * 448;
  u16* W2   = qf + (size_t)16384 * 1024;
  float* cvec = (float*)(W2 + (size_t)512 * 448);

  // qk projection + L2 norm -> planar qf (128x512 tile, depth-3 A prefetch)
  gemm1<<<dim3(256), dim3(512), 0, stream>>>(x, w_qk, qf, 1024, 512);
  // cost-volume dots (dual-pipe LDS+L2 k reads) -> corr; W2/cvec prep (merged)
  dots_w2<<<dim3(1024), dim3(256), 0, stream>>>(qf, corr, w_proj, w_corr,
                                                b_corr, b_proj, W2, cvec);
  // out = corr @ W2^T + cvec  (K=448)
  gemm2b<<<dim3(1024), dim3(256), 0, stream>>>(corr, W2, cvec, out, 512, 448);
}

// Round 23
// 73.998 us; speedup vs baseline: 1.3337x; 1.3337x over previous
//
#include <hip/hip_runtime.h>

typedef unsigned int u32;
typedef unsigned short u16;
typedef __fp16 h2 __attribute__((ext_vector_type(2)));
typedef __fp16 f16x8 __attribute__((ext_vector_type(8)));
typedef float f32x4 __attribute__((ext_vector_type(4)));

#define DEVFN static __device__ __forceinline__

DEVFN u32 pkh(float a, float b) {
  return __builtin_bit_cast(u32, __builtin_amdgcn_cvt_pkrtz(a, b));
}
DEVFN u16 f2h(float f) { __fp16 h = (__fp16)f; return __builtin_bit_cast(u16, h); }

#if __has_builtin(__builtin_amdgcn_fdot2)
DEVFN float dot2u(u32 a, u32 b, float c) {
  return __builtin_amdgcn_fdot2(__builtin_bit_cast(h2, a),
                                __builtin_bit_cast(h2, b), c, false);
}
#else
DEVFN float dot2u(u32 a, u32 b, float c) {
  h2 x = __builtin_bit_cast(h2, a), y = __builtin_bit_cast(h2, b);
  return c + (float)x[0] * (float)y[0] + (float)x[1] * (float)y[1];
}
#endif

DEVFN uint4 pk8(f32x4 lo, f32x4 hi) {
  uint4 o;
  o.x = pkh(lo.x, lo.y); o.y = pkh(lo.z, lo.w);
  o.z = pkh(hi.x, hi.y); o.w = pkh(hi.z, hi.w);
  return o;
}

DEVFN void gld16(const u16* g, u16* l) {
  __builtin_amdgcn_global_load_lds(
      (const __attribute__((address_space(1))) u32*)g,
      (__attribute__((address_space(3))) u32*)l, 16, 0, 0);
}

DEVFN void waitl0() { asm volatile("s_waitcnt lgkmcnt(0)" ::: "memory"); }
DEVFN void rbar() {
  __builtin_amdgcn_sched_barrier(0);
  __builtin_amdgcn_s_barrier();
  __builtin_amdgcn_sched_barrier(0);
}

// GEMM1: C = A @ B^T, f32 reg-staged dbuf raw-barrier pipeline (r19/r21
// verified optimum). BM=128 x BN=512, 512 threads (8 waves 2x4), 256 blocks.
// A depth-3 prefetch (two named reg sets E/O), B depth-2.
// Epilogue: per-64-col-group L2 norm, scatter to PLANAR qf
// [sel][b][t][h][1024px][64] f16, fr = ((sel*2+b)*8+t)*8+h.
__global__ __launch_bounds__(512) void gemm1(
    const float* __restrict__ Af, const float* __restrict__ Bf,
    u16* __restrict__ Out, int Nn, int K) {
  __shared__ u16 As[2][4096];    // [128][32]
  __shared__ u16 Bs[2][16384];   // [512][32]
  const int tid = threadIdx.x;
  const int lane = tid & 63;
  const int w = tid >> 6;
  const int wm = w >> 2, wn = w & 3;
  const int nwg = (int)gridDim.x;     // 256
  const int wg = ((int)blockIdx.x & 7) * (nwg >> 3) + ((int)blockIdx.x >> 3);
  const int tm = wg >> 1, tn = wg & 1;

  const int ra = tid >> 2;
  const int s8 = (tid & 3) << 3;
  const size_t offA = (size_t)(tm * 128 + ra) * K + s8;
  const size_t offB = (size_t)(tn * 512 + ra) * K + s8;
  const int wofs = ra * 32 + s8;

  const int rofsA = ((wm * 64 + (lane & 15)) << 5) + ((lane >> 4) << 3);
  const int rofsB = ((wn * 128 + (lane & 15)) << 5) + ((lane >> 4) << 3);

  f32x4 acc[4][8] = {};
  f32x4 ae0, ae1, ao0, ao1;                       // A sets E / O
  f32x4 b0, b1, b2, b3, b4, b5, b6, b7;           // B set

#define LOADA_E(t)                                                        \
  {                                                                       \
    const size_t oa = offA + (size_t)(t) * 32;                            \
    ae0 = *(const f32x4*)(Af + oa);                                       \
    ae1 = *(const f32x4*)(Af + oa + 4);                                   \
  }
#define LOADA_O(t)                                                        \
  {                                                                       \
    const size_t oa = offA + (size_t)(t) * 32;                            \
    ao0 = *(const f32x4*)(Af + oa);                                       \
    ao1 = *(const f32x4*)(Af + oa + 4);                                   \
  }
#define LOADB(t)                                                          \
  {                                                                       \
    const size_t ob = offB + (size_t)(t) * 32;                            \
    b0 = *(const f32x4*)(Bf + ob);                                        \
    b1 = *(const f32x4*)(Bf + ob + 4);                                    \
    b2 = *(const f32x4*)(Bf + ob + (size_t)128 * K);                      \
    b3 = *(const f32x4*)(Bf + ob + (size_t)128 * K + 4);                  \
    b4 = *(const f32x4*)(Bf + ob + (size_t)256 * K);                      \
    b5 = *(const f32x4*)(Bf + ob + (size_t)256 * K + 4);                  \
    b6 = *(const f32x4*)(Bf + ob + (size_t)384 * K);                      \
    b7 = *(const f32x4*)(Bf + ob + (size_t)384 * K + 4);                  \
  }
#define WRITE_E(bufi)                                                     \
  {                                                                       \
    *(uint4*)(&As[bufi][wofs]) = pk8(ae0, ae1);                           \
    *(uint4*)(&Bs[bufi][wofs]) = pk8(b0, b1);                             \
    *(uint4*)(&Bs[bufi][wofs + 4096]) = pk8(b2, b3);                      \
    *(uint4*)(&Bs[bufi][wofs + 8192]) = pk8(b4, b5);                      \
    *(uint4*)(&Bs[bufi][wofs + 12288]) = pk8(b6, b7);                     \
  }
#define WRITE_O(bufi)                                                     \
  {                                                                       \
    *(uint4*)(&As[bufi][wofs]) = pk8(ao0, ao1);                           \
    *(uint4*)(&Bs[bufi][wofs]) = pk8(b0, b1);                             \
    *(uint4*)(&Bs[bufi][wofs + 4096]) = pk8(b2, b3);                      \
    *(uint4*)(&Bs[bufi][wofs + 8192]) = pk8(b4, b5);                      \
    *(uint4*)(&Bs[bufi][wofs + 12288]) = pk8(b6, b7);                     \
  }
#define FRAGS(bufi)                                                       \
  f16x8 af[4], bf[8];                                                     \
  _Pragma("unroll") for (int i = 0; i < 4; ++i)                           \
      af[i] = *(const f16x8*)(&As[bufi][rofsA + i * 512]);                \
  _Pragma("unroll") for (int i = 0; i < 8; ++i)                           \
      bf[i] = *(const f16x8*)(&Bs[bufi][rofsB + i * 512]);
#define MFMAS                                                             \
  __builtin_amdgcn_s_setprio(1);                                          \
  _Pragma("unroll") for (int mi = 0; mi < 4; ++mi)                        \
      _Pragma("unroll") for (int ni = 0; ni < 8; ++ni)                    \
          acc[mi][ni] = __builtin_amdgcn_mfma_f32_16x16x32_f16(           \
              af[mi], bf[ni], acc[mi][ni], 0, 0, 0);                      \
  __builtin_amdgcn_s_setprio(0);

  const int KT = K >> 5;   // 16 (even)
  // prologue: tile0 staged (A set E); A(1)->O, A(2)->E, B(1) in flight
  LOADA_E(0)
  LOADB(0)
  WRITE_E(0)
  LOADA_O(1)
  LOADA_E(2)
  LOADB(1)
  waitl0();
  rbar();

  for (int kt = 0; kt < KT; kt += 2) {
    {  // even body: cur=0; write tile kt+1 (A set O); load A(kt+3)->O
      FRAGS(0)
      if (kt + 1 < KT) {
        WRITE_O(1)
        if (kt + 2 < KT) LOADB(kt + 2)
        if (kt + 3 < KT) LOADA_O(kt + 3)
      }
      MFMAS
      waitl0();
      rbar();
    }
    {  // odd body: cur=1; write tile kt+2 (A set E); load A(kt+4)->E
      FRAGS(1)
      if (kt + 2 < KT) {
        WRITE_E(0)
        if (kt + 3 < KT) LOADB(kt + 3)
        if (kt + 4 < KT) LOADA_E(kt + 4)
      }
      MFMAS
      waitl0();
      rbar();
    }
  }
#undef LOADA_E
#undef LOADA_O
#undef LOADB
#undef WRITE_E
#undef WRITE_O
#undef FRAGS
#undef MFMAS

  // epilogue: two 64-col groups per wave tile (lo = ni 0..3, hi = ni 4..7)
  const int rowBase = tm * 128 + wm * 64 + ((lane >> 4) << 2);
  const int colLo = tn * 512 + wn * 128;
  const int colHi = colLo + 64;
  const int selLo = colLo >> 9, hhLo = (colLo >> 6) & 7;
  const int selHi = colHi >> 9, hhHi = (colHi >> 6) & 7;
  const int ddb = lane & 15;
#pragma unroll
  for (int mi = 0; mi < 4; ++mi)
#pragma unroll
    for (int r = 0; r < 4; ++r) {
      float sl = acc[mi][0][r] * acc[mi][0][r] + acc[mi][1][r] * acc[mi][1][r] +
                 acc[mi][2][r] * acc[mi][2][r] + acc[mi][3][r] * acc[mi][3][r];
      float sh = acc[mi][4][r] * acc[mi][4][r] + acc[mi][5][r] * acc[mi][5][r] +
                 acc[mi][6][r] * acc[mi][6][r] + acc[mi][7][r] * acc[mi][7][r];
      sl += __shfl_xor(sl, 1); sh += __shfl_xor(sh, 1);
      sl += __shfl_xor(sl, 2); sh += __shfl_xor(sh, 2);
      sl += __shfl_xor(sl, 4); sh += __shfl_xor(sh, 4);
      sl += __shfl_xor(sl, 8); sh += __shfl_xor(sh, 8);
      float invl = 1.0f / fmaxf(sqrtf(sl), 1e-12f);
      float invh = 1.0f / fmaxf(sqrtf(sh), 1e-12f);
      const int m = rowBase + mi * 16 + r;
      const int bb = m >> 13, tt = (m >> 10) & 7, pix = m & 1023;
      const size_t pxo = (size_t)pix * 64 + ddb;
      const int frL = ((selLo * 2 + bb) * 8 + tt) * 8 + hhLo;
      const int frH = ((selHi * 2 + bb) * 8 + tt) * 8 + hhHi;
      size_t baseL = (((size_t)frL) << 16) + pxo;
      size_t baseH = (((size_t)frH) << 16) + pxo;
#pragma unroll
      for (int ni = 0; ni < 4; ++ni) {
        Out[baseL + ni * 16] = f2h(acc[mi][ni][r] * invl);
        Out[baseH + ni * 16] = f2h(acc[mi][ni + 4][r] * invh);
      }
    }
}

// GEMM2b: out = A @ B^T + bias.  A [M][448] f16 (corr), B [512][448] f16 (W2).
// BM=64 x BN=128 -> 1024 blocks, BK=64 as two [.][32] subtiles/round.
__global__ __launch_bounds__(256) void gemm2b(
    const u16* __restrict__ A, const u16* __restrict__ B,
    const float* __restrict__ bias, float* __restrict__ Out,
    int Nn, int K) {
  __shared__ u16 As[2][2048];
  __shared__ u16 Bs[2][4096];
  const int tid = threadIdx.x;
  const int lane = tid & 63;
  const int w = tid >> 6;
  const int nwg = (int)gridDim.x;
  const int wg = ((int)blockIdx.x & 7) * (nwg >> 3) + ((int)blockIdx.x >> 3);
  const int tm = wg >> 2, tn = wg & 3;

  const u16* gA = A + (size_t)(tm * 64 + w * 16 + (lane >> 2)) * K +
                  ((lane & 3) << 3);
  const u16* gB = B + (size_t)(tn * 128 + w * 32 + (lane >> 2)) * K +
                  ((lane & 3) << 3);

  const int rofsA = ((lane & 15) << 5) + ((lane >> 4) << 3);
  const int rofsB = w * 1024 + ((lane & 15) << 5) + ((lane >> 4) << 3);

  f32x4 acc[4][2] = {};

#define STG(bufi, t)                                                      \
  {                                                                       \
    gld16(gA + (size_t)(t) * 32, &As[bufi][w * 512]);                     \
    gld16(gB + (size_t)(t) * 32, &Bs[bufi][w * 1024]);                    \
    gld16(gB + (size_t)(t) * 32 + (size_t)16 * K, &Bs[bufi][w * 1024 + 512]); \
  }

  const int KT = K >> 6;   // 448/64 = 7
  for (int kt = 0; kt < KT; ++kt) {
    __syncthreads();
    STG(0, 2 * kt)
    STG(1, 2 * kt + 1)
    __syncthreads();
#pragma unroll
    for (int sub = 0; sub < 2; ++sub) {
      f16x8 af[4], bf[2];
#pragma unroll
      for (int i = 0; i < 4; ++i)
        af[i] = *(const f16x8*)(&As[sub][rofsA + i * 512]);
#pragma unroll
      for (int i = 0; i < 2; ++i)
        bf[i] = *(const f16x8*)(&Bs[sub][rofsB + i * 512]);
#pragma unroll
      for (int mi = 0; mi < 4; ++mi)
#pragma unroll
        for (int ni = 0; ni < 2; ++ni)
          acc[mi][ni] = __builtin_amdgcn_mfma_f32_16x16x32_f16(
              af[mi], bf[ni], acc[mi][ni], 0, 0, 0);
    }
  }
#undef STG

  const int rowBase = tm * 64 + ((lane >> 4) << 2);
  const int colBase = tn * 128 + w * 32 + (lane & 15);
  float bv[2];
#pragma unroll
  for (int ni = 0; ni < 2; ++ni) bv[ni] = bias[colBase + ni * 16];
#pragma unroll
  for (int mi = 0; mi < 4; ++mi)
#pragma unroll
    for (int r = 0; r < 4; ++r) {
      size_t ro = (size_t)(rowBase + mi * 16 + r) * Nn;
#pragma unroll
      for (int ni = 0; ni < 2; ++ni)
        Out[ro + colBase + ni * 16] = acc[mi][ni][r] + bv[ni];
    }
}

// Merged, 256 threads: blocks 0..511 = dots (corr[448]); 512..1023 = W2/cvec.
__global__ __launch_bounds__(256) void dots_w2(
    const u16* __restrict__ qf, u16* __restrict__ corr,
    const float* __restrict__ wp, const float* __restrict__ wc,
    const float* __restrict__ bc, const float* __restrict__ bp,
    u16* __restrict__ W2, float* __restrict__ cvec) {
  __shared__ __align__(16) u16 smem[448 * 64];  // 56KB
  const int tid = threadIdx.x;

  if ((int)blockIdx.x >= 512) {
    const int o = (int)blockIdx.x - 512;
    float* wcl = (float*)smem;
    float* wpl = wcl + 3136;
    for (int i = tid; i < 3136; i += 256) wcl[i] = wc[i];
    wpl[tid] = wp[o * 512 + tid];
    wpl[tid + 256] = wp[o * 512 + tid + 256];
    __syncthreads();
#pragma unroll
    for (int pass = 0; pass < 2; ++pass) {
      const int idx = pass * 256 + tid;
      if (idx < 448) {
        const int hh = idx / 56, r = idx % 56, du = r >> 3, dv = r & 7;
        float sv = 0.f;
        if (dv < 7) {
#pragma unroll
          for (int c = 0; c < 64; ++c)
            sv += wpl[hh * 64 + c] * wcl[c * 49 + du * 7 + dv];
        }
        W2[o * 448 + idx] = f2h(sv);
      }
    }
    if (tid < 64) {
      float p = 0.f;
#pragma unroll
      for (int g = 0; g < 8; ++g) p += wpl[g * 64 + tid];
      p *= bc[tid];
      p += __shfl_xor(p, 1); p += __shfl_xor(p, 2); p += __shfl_xor(p, 4);
      p += __shfl_xor(p, 8); p += __shfl_xor(p, 16); p += __shfl_xor(p, 32);
      if (tid == 0) cvec[o] = p + bp[o];
    }
    return;
  }

  u16* kst = smem;
  const int bid = ((int)blockIdx.x & 7) * 64 + ((int)blockIdx.x >> 3);  // XCD
  const int fr = bid >> 2, grp = bid & 3;
  const int h = fr & 7, t = (fr >> 3) & 7, b = fr >> 6;
  const int t1 = (t < 7) ? t + 1 : 7;
  const int y0 = grp * 8;

  const u16* kbase = qf + (((size_t)(((2 + b) * 8 + t1) * 8 + h)) << 16);
  {
    const int ppx = tid >> 3;
    const int slot = tid & 7;
#pragma unroll
    for (int pass = 0; pass < 14; ++pass) {
      int gy = y0 - 3 + pass;
      uint4 v = make_uint4(0, 0, 0, 0);
      if ((unsigned)gy < 32u)
        v = *(const uint4*)(kbase + (size_t)(gy * 32 + ppx) * 64 + slot * 8);
      int pl = pass * 32 + ppx;
      *(uint4*)((char*)kst + pl * 128 + ((slot * 16) ^ ((pl & 7) << 4))) = v;
    }
  }

  const int px = grp * 256 + tid;
  const int x = tid & 31, yloc = tid >> 5;
  const u16* qp = qf + (((size_t)fr) << 16) + (size_t)px * 64;
  u32 qw[32];
#pragma unroll
  for (int j = 0; j < 8; ++j) {
    uint4 v = *(const uint4*)(qp + j * 8);
    qw[j * 4 + 0] = v.x; qw[j * 4 + 1] = v.y;
    qw[j * 4 + 2] = v.z; qw[j * 4 + 3] = v.w;
  }
  __syncthreads();

  u16* mp = corr + (size_t)((b * 8 + t) * 1024 + px) * 448 + h * 56;
  for (int du = 0; du < 7; ++du) {
    const int rlbase = (yloc + du) * 32;
    float f[7];
#pragma unroll
    for (int dv = 0; dv < 7; ++dv) {
      int xx = x + dv - 3;
      int xc = xx < 0 ? 0 : (xx > 31 ? 31 : xx);
      int pl = rlbase + xc;
      const char* kr = (const char*)kst + pl * 128;
      const int swz = (pl & 7) << 4;
      float s0 = 0.f, s1 = 0.f, s2 = 0.f, s3 = 0.f;
#pragma unroll
      for (int j = 0; j < 8; ++j) {
        uint4 v = *(const uint4*)(kr + ((j * 16) ^ swz));
        s0 = dot2u(qw[j * 4 + 0], v.x, s0);
        s1 = dot2u(qw[j * 4 + 1], v.y, s1);
        s2 = dot2u(qw[j * 4 + 2], v.z, s2);
        s3 = dot2u(qw[j * 4 + 3], v.w, s3);
      }
      float s = (s0 + s1) + (s2 + s3);
      f[dv] = ((unsigned)xx < 32u) ? s : 0.f;
    }
    uint4 o;
    o.x = pkh(f[0], f[1]); o.y = pkh(f[2], f[3]);
    o.z = pkh(f[4], f[5]); o.w = pkh(f[6], 0.f);
    *(uint4*)(mp + du * 8) = o;
  }
}

extern "C" void kernel_launch(void* const* d_in, const int* in_sizes, int n_in,
                              void* d_out, int out_size, void* d_ws, size_t ws_size,
                              hipStream_t stream) {
  const float* x      = (const float*)d_in[0];  // [2,8192,512] f32
  const float* w_qk   = (const float*)d_in[1];  // [1024,512]   f32
  const float* w_corr = (const float*)d_in[2];  // [64,49]      f32
  const float* b_corr = (const float*)d_in[3];  // [64]         f32
  const float* w_proj = (const float*)d_in[4];  // [512,512]    f32
  const float* b_proj = (const float*)d_in[5];  // [512]        f32
  float* out = (float*)d_out;                   // [2,8192,512] f32

  u16* corr = (u16*)d_ws;
  u16* qf   = corr + (size_t)16384 * 448;
  u16* W2   = qf + (size_t)16384 * 1024;
  float* cvec = (float*)(W2 + (size_t)512 * 448);

  // qk projection + L2 norm -> planar qf (128x512 tile, depth-3 A prefetch)
  gemm1<<<dim3(256), dim3(512), 0, stream>>>(x, w_qk, qf, 1024, 512);
  // cost-volume dots -> corr[16384][448]; W2/cvec prep (merged)
  dots_w2<<<dim3(1024), dim3(256), 0, stream>>>(qf, corr, w_proj, w_corr,
                                                b_corr, b_proj, W2, cvec);
  // out = corr @ W2^T + cvec  (K=448)
  gemm2b<<<dim3(1024), dim3(256), 0, stream>>>(corr, W2, cvec, out, 512, 448);
}